// Round 13
// baseline (1815.397 us; speedup 1.0000x reference)
//
#include <hip/hip_runtime.h>
#include <cstdint>
#include <cstddef>
#include <math.h>

#define NANCH    36864
#define NPRE     12000
#define NPRE_PAD 12032
#define NW       188
#define SORT_N   16384
#define NPOST    2000

typedef double d4_t __attribute__((ext_vector_type(4)));

__device__ __forceinline__ int tribase(int ci) { return ci * NW - (ci * (ci - 1)) / 2; }

typedef __attribute__((address_space(1))) const void* as1cv_t;
typedef __attribute__((address_space(3))) void* as3v_t;
__device__ __forceinline__ void gload_lds16(const float* g, float* l)
{
    __builtin_amdgcn_global_load_lds((as1cv_t)g, (as3v_t)l, 16, 0, 0);
}

// ---------------------------------------------------------------------------
// K1: f64-MFMA implicit-GEMM 3x3 conv (1024ic -> 512oc, 64x64), bias+leaky
// fused, f32 h out. Grid 512 = 64 y x 8 oc-tiles (2 blk/CU). 4 waves (2x2),
// wave = 32x32 via 2x2 mfma_f64_16x16x4. Probe-calibrated lane maps (r4).
// r9 schedule (782us, MfmaUtil 68%): 2-ahead staging, counted vmcnt(12),
// step-0 reg preload. FROZEN.
// ---------------------------------------------------------------------------
__global__ __launch_bounds__(256, 2)
void k_conv_mfma(const float* __restrict__ xg, const float* __restrict__ wg_,
                 const float* __restrict__ bg, float* __restrict__ hg)
{
    __shared__ __align__(16) float wlds[3][4608];   // 3 x 18 slots x (64oc x 4k)
    __shared__ __align__(16) float xlds[3][1632];   // 3 x 8ic x 3row x 68col
    const int tid = threadIdx.x;
    const int oct = blockIdx.x & 7;
    const int y   = blockIdx.x >> 3;
    const int oc0 = oct << 6;
    const int l   = tid & 63;       // lane
    const int wv  = tid >> 6;       // wave 0..3
    const int g   = l >> 4;         // k-group label
    const int li  = l & 15;
    const int wm  = wv >> 1;        // px-half
    const int wn  = wv & 1;         // oc-half
    const int slot5 = 16 + (wv & 1); // 5th gll slot (dup-identical for wv 2,3)

    // ---- layout probe (3 constant-input MFMAs) — proven in r4 ----
    int pr[4], qc[4];
    int aG = g;
    {
        d4_t Pz = {0., 0., 0., 0.}, Qz = {0., 0., 0., 0.}, Tz = {0., 0., 0., 0.};
        Pz = __builtin_amdgcn_mfma_f64_16x16x4f64((double)li, 1.0, Pz, 0, 0, 0);
        Qz = __builtin_amdgcn_mfma_f64_16x16x4f64(1.0, (double)li, Qz, 0, 0, 0);
        Tz = __builtin_amdgcn_mfma_f64_16x16x4f64((double)g, (double)(1 << (2 * g)),
                                                  Tz, 0, 0, 0);
        bool ok = true;
        const int tval = (int)Tz[0];
        if ((int)Tz[1] != tval || (int)Tz[2] != tval || (int)Tz[3] != tval) ok = false;
        int seen = 0;
#pragma unroll
        for (int j = 0; j < 4; ++j) {
            int d = (tval >> (2 * j)) & 3;
            seen |= 1 << d;
            if (d == g) aG = j;
        }
        if (seen != 15) ok = false;
#pragma unroll
        for (int r = 0; r < 4; ++r) {
            int pv = (int)Pz[r], qv = (int)Qz[r];
            if ((pv & 3) || (qv & 3)) ok = false;
            pr[r] = pv >> 2; qc[r] = qv >> 2;
            if (pr[r] > 15 || qc[r] > 15) ok = false;
        }
        if (!ok) {
#pragma unroll
            for (int r = 0; r < 4; ++r) { pr[r] = 4 * g + r; qc[r] = li; }
            aG = g;
        }
    }

    d4_t acc00 = {0., 0., 0., 0.}, acc01 = {0., 0., 0., 0.};
    d4_t acc10 = {0., 0., 0., 0.}, acc11 = {0., 0., 0., 0.};

    // x staging offsets: 8ic x 3row x 66col = 1584 floats / 256 thr -> 7 slots
    int xoff[7], loff[7];
#pragma unroll
    for (int t = 0; t < 7; ++t) {
        int f = tid + 256 * t;
        if (f < 1584) {
            int ic = f / 198; int r = f - ic * 198; int sr = r / 66; int gc = r - sr * 66;
            loff[t] = (ic * 3 + sr) * 68 + gc;
            int gy = y + sr - 1, gx = gc - 1;
            xoff[t] = (gy >= 0 && gy < 64 && gx >= 0 && gx < 64)
                      ? (ic * 4096 + gy * 64 + gx) : -1;
        } else { loff[t] = -1; xoff[t] = -1; }
    }
    int xoffL[7];                    // clamped: always-valid load address
#pragma unroll
    for (int t = 0; t < 7; ++t) xoffL[t] = (xoff[t] >= 0) ? xoff[t] : 0;

    const float* wsrc0 = wg_ + (size_t)(oc0 + l) * 9216;  // per-lane W row base
    const int abase = wm * 32 + li;
    const int bbase = (wn * 32 + li) * 4 + g;
    const int ax0   = (aG / 3) * 68 + (aG - 3 * (aG / 3)) + abase;  // step-0 A addr
    float xr[7];
    float fa0, fa1, fb0, fb1;
    double pa0, pa1, pb0, pb1;

    // ---- prologue: stage chunks 0,1; xr <- x(2); preload step0(0) ----
    {
#pragma unroll
        for (int i = 0; i < 4; ++i)
            gload_lds16(wsrc0 + 4 * (wv + 4 * i), &wlds[0][(wv + 4 * i) * 256]);
        gload_lds16(wsrc0 + 4 * slot5, &wlds[0][slot5 * 256]);
#pragma unroll
        for (int i = 0; i < 4; ++i)
            gload_lds16(wsrc0 + 72 + 4 * (wv + 4 * i), &wlds[1][(wv + 4 * i) * 256]);
        gload_lds16(wsrc0 + 72 + 4 * slot5, &wlds[1][slot5 * 256]);
#pragma unroll
        for (int t = 0; t < 7; ++t) xr[t] = xg[xoffL[t]];
#pragma unroll
        for (int t = 0; t < 7; ++t)
            if (loff[t] >= 0) xlds[0][loff[t]] = (xoff[t] >= 0) ? xr[t] : 0.f;
        {
            const float* xp = xg + 32768;
#pragma unroll
            for (int t = 0; t < 7; ++t) xr[t] = xp[xoffL[t]];
#pragma unroll
            for (int t = 0; t < 7; ++t)
                if (loff[t] >= 0) xlds[1][loff[t]] = (xoff[t] >= 0) ? xr[t] : 0.f;
        }
        {
            const float* xp = xg + 2 * 32768;
#pragma unroll
            for (int t = 0; t < 7; ++t) xr[t] = xp[xoffL[t]];
        }
        asm volatile("s_waitcnt lgkmcnt(0)" ::: "memory");
        asm volatile("s_waitcnt vmcnt(7)" ::: "memory");   // x(2) may still fly
        __builtin_amdgcn_s_barrier();
        fa0 = xlds[0][ax0]; fa1 = xlds[0][ax0 + 16];
        fb0 = wlds[0][bbase]; fb1 = wlds[0][bbase + 64];
        asm volatile("s_waitcnt lgkmcnt(0)" ::: "memory");
        pa0 = (double)fa0; pa1 = (double)fa1; pb0 = (double)fb0; pb1 = (double)fb1;
    }

#pragma unroll 1
    for (int cc = 0; cc < 128; ++cc) {
        int cb = cc % 3, nb = (cc + 1) % 3, sb = (cc + 2) % 3;
        if (cc + 2 < 128) {
            // stage chunk cc+2: exactly 5 gll + 7 x loads / thread
            const float* wsrc = wsrc0 + (cc + 2) * 72;
            float* wdst = &wlds[sb][0];
#pragma unroll
            for (int i = 0; i < 4; ++i)
                gload_lds16(wsrc + 4 * (wv + 4 * i), wdst + (wv + 4 * i) * 256);
            gload_lds16(wsrc + 4 * slot5, wdst + slot5 * 256);
            float* xdst = &xlds[sb][0];
#pragma unroll
            for (int t = 0; t < 7; ++t)
                if (loff[t] >= 0) xdst[loff[t]] = (xoff[t] >= 0) ? xr[t] : 0.f;
            {
                int nc = (cc + 3 < 128) ? (cc + 3) : 127;
                const float* xp = xg + (size_t)nc * 32768;
#pragma unroll
                for (int t = 0; t < 7; ++t) xr[t] = xp[xoffL[t]];
            }
            asm volatile("s_waitcnt vmcnt(12)" ::: "memory"); // staging(cc+1) landed
        } else {
            asm volatile("s_waitcnt vmcnt(0)" ::: "memory");
        }
        __builtin_amdgcn_s_barrier();                          // #1: publish buf[nb]
        __builtin_amdgcn_sched_barrier(0);

        // compute chunk cc: step0 from p-regs, steps 1..17 from LDS
        const float* wb = &wlds[cb][0];
        const float* xb = &xlds[cb][0];
        __builtin_amdgcn_s_setprio(1);
        acc00 = __builtin_amdgcn_mfma_f64_16x16x4f64(pa0, pb0, acc00, 0, 0, 0);
        acc01 = __builtin_amdgcn_mfma_f64_16x16x4f64(pa0, pb1, acc01, 0, 0, 0);
        acc10 = __builtin_amdgcn_mfma_f64_16x16x4f64(pa1, pb0, acc10, 0, 0, 0);
        acc11 = __builtin_amdgcn_mfma_f64_16x16x4f64(pa1, pb1, acc11, 0, 0, 0);
#pragma unroll
        for (int s = 1; s < 18; ++s) {
            int k   = 4 * s + aG;
            int icL = k / 9; int tap = k - 9 * icL;
            int ky  = tap / 3; int kx = tap - 3 * ky;
            int ax  = (icL * 3 + ky) * 68 + kx + abase;
            double a0 = (double)xb[ax];
            double a1 = (double)xb[ax + 16];
            double b0 = (double)wb[bbase + s * 256];
            double b1 = (double)wb[bbase + s * 256 + 64];
            acc00 = __builtin_amdgcn_mfma_f64_16x16x4f64(a0, b0, acc00, 0, 0, 0);
            acc01 = __builtin_amdgcn_mfma_f64_16x16x4f64(a0, b1, acc01, 0, 0, 0);
            acc10 = __builtin_amdgcn_mfma_f64_16x16x4f64(a1, b0, acc10, 0, 0, 0);
            acc11 = __builtin_amdgcn_mfma_f64_16x16x4f64(a1, b1, acc11, 0, 0, 0);
        }
        __builtin_amdgcn_s_setprio(0);
        __builtin_amdgcn_sched_barrier(0);   // pin compute reads before preload

        if (cc < 127) {
            // preload step0 of chunk cc+1 (buf[nb] published at bar#1 above)
            fa0 = xlds[nb][ax0]; fa1 = xlds[nb][ax0 + 16];
            fb0 = wlds[nb][bbase]; fb1 = wlds[nb][bbase + 64];
            asm volatile("s_waitcnt lgkmcnt(4)" ::: "memory"); // compute reads drained
            __builtin_amdgcn_s_barrier();                      // #2: reuse fence
            asm volatile("s_waitcnt lgkmcnt(0)" ::: "memory"); // preload landed
            pa0 = (double)fa0; pa1 = (double)fa1; pb0 = (double)fb0; pb1 = (double)fb1;
        } else {
            asm volatile("s_waitcnt lgkmcnt(0)" ::: "memory");
            __builtin_amdgcn_s_barrier();
        }
    }

    // epilogue: bias + leaky in f64, probe-derived labels, LDS transpose, f32 out
    __syncthreads();
    float* olds = &wlds[0][0];                    // 4352 floats needed <= 4608
    {
#pragma unroll
        for (int r = 0; r < 4; ++r) {
            const int oca = wn * 32 + qc[r];
            const int ocb = oca + 16;
            const double ba = (double)bg[oc0 + oca];
            const double bb = (double)bg[oc0 + ocb];
            const int pxa = wm * 32 + pr[r];
            const int pxb = pxa + 16;
            double t00 = acc00[r] + ba;
            double t01 = acc01[r] + bb;
            double t10 = acc10[r] + ba;
            double t11 = acc11[r] + bb;
            olds[oca * 68 + pxa] = (float)((t00 >= 0.0) ? t00 : 0.01 * t00);
            olds[ocb * 68 + pxa] = (float)((t01 >= 0.0) ? t01 : 0.01 * t01);
            olds[oca * 68 + pxb] = (float)((t10 >= 0.0) ? t10 : 0.01 * t10);
            olds[ocb * 68 + pxb] = (float)((t11 >= 0.0) ? t11 : 0.01 * t11);
        }
    }
    __syncthreads();
    {
        const int oc = tid >> 2, q = tid & 3;     // 4 threads per oc, 16 px each
        float* dst = hg + (size_t)(oc0 + oc) * 4096 + y * 64 + q * 16;
        const float* src = &olds[oc * 68 + q * 16];
#pragma unroll
        for (int j = 0; j < 4; ++j)
            *(float4*)(dst + 4 * j) = *(const float4*)(src + 4 * j);
    }
}

// ---------------------------------------------------------------------------
// K2: 1x1 convs (f64 accumulate) + f64 sort keys + anchors + f32 box deparam
// ---------------------------------------------------------------------------
__global__ __launch_bounds__(256, 1)
void k_heads(const float* __restrict__ hg, const float* __restrict__ loc_w,
             const float* __restrict__ loc_b, const float* __restrict__ score_w,
             const float* __restrict__ score_b, const int* __restrict__ imh,
             const int* __restrict__ imw, float* __restrict__ out,
             float* __restrict__ boxes_all, unsigned long long* __restrict__ keys64)
{
    __shared__ float  hch[64 * 64];
    __shared__ float  wch[54 * 64];
    __shared__ float  ol[54 * 64];
    __shared__ double sld[18 * 64];
    const int y = blockIdx.x, tid = threadIdx.x;
    const int px = tid & 63, cg = tid >> 6;
    double acc[14];
#pragma unroll
    for (int u = 0; u < 14; ++u) acc[u] = 0.0;
    for (int cc = 0; cc < 8; ++cc) {
        __syncthreads();
#pragma unroll
        for (int t = 0; t < 16; ++t) {
            int f = tid + 256 * t;
            hch[f] = hg[(size_t)(cc * 64 + (f >> 6)) * 4096 + y * 64 + (f & 63)];
        }
#pragma unroll
        for (int t = 0; t < 14; ++t) {
            int f = tid + 256 * t;
            if (f < 54 * 64) {
                int ch = f >> 6, c = f & 63;
                wch[f] = (ch < 36) ? loc_w[ch * 512 + cc * 64 + c]
                                   : score_w[(ch - 36) * 512 + cc * 64 + c];
            }
        }
        __syncthreads();
        for (int c = 0; c < 64; ++c) {
            double hvd = (double)hch[c * 64 + px];
#pragma unroll
            for (int u = 0; u < 14; ++u) {
                int ch = cg + 4 * u;
                if (ch < 54) acc[u] = fma((double)wch[ch * 64 + c], hvd, acc[u]);
            }
        }
    }
    __syncthreads();
#pragma unroll
    for (int u = 0; u < 14; ++u) {
        int ch = cg + 4 * u;
        if (ch < 54) {
            double s = acc[u] + (double)((ch < 36) ? loc_b[ch] : score_b[ch - 36]);
            ol[ch * 64 + px] = (float)s;
            if (ch >= 36) sld[(ch - 36) * 64 + px] = s;
        }
    }
    __syncthreads();
    for (int f = tid; f < 64 * 36; f += 256) {
        int p = f / 36, ch = f - 36 * p;
        out[(size_t)(y * 64 + p) * 36 + ch] = ol[ch * 64 + p];
    }
    for (int f = tid; f < 64 * 18; f += 256) {
        int p = f / 18, ch = f - 18 * p;
        out[147456 + (size_t)(y * 64 + p) * 18 + ch] = ol[(36 + ch) * 64 + p];
    }
    const float fy = (float)(*imh), fx = (float)(*imw);
    float* anch = out + 229184;
    for (int t2 = tid; t2 < 576; t2 += 256) {
        int p = t2 / 9, a = t2 - 9 * p;
        int pg = y * 64 + p;
        int ar = a / 3, as = a - 3 * ar;
        double rr = (ar == 0) ? 0.5 : ((ar == 1) ? 1.0 : 2.0);
        double ss = (as == 0) ? 8.0 : ((as == 1) ? 16.0 : 32.0);
        double hh = 16.0 * ss * sqrt(rr), wwd = 16.0 * ss * sqrt(1.0 / rr);
        float by1 = (float)(8.0 - hh * 0.5), bx1 = (float)(8.0 - wwd * 0.5);
        float by2 = (float)(8.0 + hh * 0.5), bx2 = (float)(8.0 + wwd * 0.5);
        float sy = (float)(y * 16), sx = (float)(p * 16);
        float a0 = sy + by1, a1 = sx + bx1, a2 = sy + by2, a3 = sx + bx2;
        int base = (pg * 9 + a) * 4;
        anch[base + 0] = a0; anch[base + 1] = a1; anch[base + 2] = a2; anch[base + 3] = a3;
        double d = sld[(a * 2 + 1) * 64 + p] - sld[(a * 2) * 64 + p];
        long long bits = __double_as_longlong(d);
        unsigned long long u64 =
            (unsigned long long)(bits ^ ((bits >> 63) | (long long)0x8000000000000000LL));
        unsigned long long v = ~u64;
        keys64[pg * 9 + a] = (v & 0xFFFFFFFFFFFF0000ULL) | (unsigned long long)(pg * 9 + a);
        float dy = ol[(a * 4 + 0) * 64 + p], dxv = ol[(a * 4 + 1) * 64 + p];
        float dh = ol[(a * 4 + 2) * 64 + p], dwv = ol[(a * 4 + 3) * 64 + p];
        float hA = a2 - a0, wA = a3 - a1;
        float cya = a0 + 0.5f * hA, cxa = a1 + 0.5f * wA;
        float cy = dy * hA + cya, cx = dxv * wA + cxa;
        float hb = hA * expf(dh), wb = wA * expf(dwv);
        float b0 = fminf(fmaxf(cy - 0.5f * hb, 0.f), fy);
        float b1 = fminf(fmaxf(cx - 0.5f * wb, 0.f), fx);
        float b2 = fminf(fmaxf(cy + 0.5f * hb, 0.f), fy);
        float b3 = fminf(fmaxf(cx + 0.5f * wb, 0.f), fx);
        boxes_all[base + 0] = b0; boxes_all[base + 1] = b1;
        boxes_all[base + 2] = b2; boxes_all[base + 3] = b3;
    }
}

// ---------------------------------------------------------------------------
// K3: radix-select 12000 smallest, compact, LDS-tiled bitonic sort.
// ---------------------------------------------------------------------------
__global__ __launch_bounds__(1024, 1)
void k_select(const unsigned long long* __restrict__ keys64,
              const float* __restrict__ boxes_all,
              unsigned long long* __restrict__ sortbuf, float* __restrict__ sbox,
              float* __restrict__ areas, unsigned long long* __restrict__ suppr)
{
    __shared__ unsigned int hist[256];
    __shared__ unsigned int sh_below, sh_prefix, sh_nsel;
    __shared__ unsigned long long tile[4096];
    const int tid = threadIdx.x;
    if (tid == 0) { sh_below = 0; sh_prefix = 0; sh_nsel = 0; }
    __syncthreads();
    for (int p = 3; p >= 0; --p) {
        if (tid < 256) hist[tid] = 0;
        __syncthreads();
        unsigned int pref = sh_prefix;
        int shift = p * 8;
        for (int i = tid; i < NANCH; i += 1024) {
            unsigned int k = (unsigned int)(keys64[i] >> 32);
            bool match = (p == 3) || ((k >> (shift + 8)) == pref);
            if (match) atomicAdd(&hist[(k >> shift) & 255u], 1u);
        }
        __syncthreads();
        if (tid == 0) {
            unsigned int below = sh_below, cacc = 0;
            int b = 0;
            for (; b < 256; ++b) {
                if (below + cacc + hist[b] >= NPRE) break;
                cacc += hist[b];
            }
            if (b > 255) b = 255;
            sh_below = below + cacc;
            sh_prefix = (pref << 8) | (unsigned int)b;
        }
        __syncthreads();
    }
    const unsigned int P = sh_prefix;
    for (int i = tid; i < NANCH; i += 1024) {
        unsigned long long k = keys64[i];
        if ((unsigned int)(k >> 32) <= P) {
            unsigned int pos = atomicAdd(&sh_nsel, 1u);
            if (pos < SORT_N) sortbuf[pos] = k;
        }
    }
    __syncthreads();
    unsigned int nsel = sh_nsel; if (nsel > SORT_N) nsel = SORT_N;
    for (unsigned int i = nsel + tid; i < SORT_N; i += 1024) sortbuf[i] = ~0ULL;
    __syncthreads();
    for (int T = 0; T < 4; ++T) {
        for (int t = tid; t < 4096; t += 1024) tile[t] = sortbuf[T * 4096 + t];
        __syncthreads();
        for (int k2 = 2; k2 <= 4096; k2 <<= 1) {
            for (int j = k2 >> 1; j > 0; j >>= 1) {
                for (int t = tid; t < 2048; t += 1024) {
                    int i = ((t & ~(j - 1)) << 1) | (t & (j - 1));
                    int ip = i | j;
                    bool up = (((T * 4096 + i) & k2) == 0);
                    unsigned long long A = tile[i], B = tile[ip];
                    if ((A > B) == up) { tile[i] = B; tile[ip] = A; }
                }
                __syncthreads();
            }
        }
        for (int t = tid; t < 4096; t += 1024) sortbuf[T * 4096 + t] = tile[t];
        __syncthreads();
    }
    auto gstage = [&](int k2, int j) {
        for (int t = tid; t < 8192; t += 1024) {
            int i = ((t & ~(j - 1)) << 1) | (t & (j - 1));
            int ip = i | j;
            bool up = ((i & k2) == 0);
            unsigned long long A = sortbuf[i], B = sortbuf[ip];
            if ((A > B) == up) { sortbuf[i] = B; sortbuf[ip] = A; }
        }
        __syncthreads();
    };
    auto ltail = [&](int k2) {
        for (int T = 0; T < 4; ++T) {
            for (int t = tid; t < 4096; t += 1024) tile[t] = sortbuf[T * 4096 + t];
            __syncthreads();
            for (int j = 2048; j > 0; j >>= 1) {
                for (int t = tid; t < 2048; t += 1024) {
                    int i = ((t & ~(j - 1)) << 1) | (t & (j - 1));
                    int ip = i | j;
                    bool up = (((T * 4096 + i) & k2) == 0);
                    unsigned long long A = tile[i], B = tile[ip];
                    if ((A > B) == up) { tile[i] = B; tile[ip] = A; }
                }
                __syncthreads();
            }
            for (int t = tid; t < 4096; t += 1024) sortbuf[T * 4096 + t] = tile[t];
            __syncthreads();
        }
    };
    gstage(8192, 4096);  ltail(8192);
    gstage(16384, 8192); gstage(16384, 4096); ltail(16384);

    if (tid < NW) suppr[tid] = (tid == NW - 1) ? 0xFFFFFFFF00000000ULL : 0ULL;
    __syncthreads();
    for (int r = tid; r < NPRE_PAD; r += 1024) {
        float b0 = 0, b1 = 0, b2 = 0, b3 = 0;
        if (r < NPRE) {
            unsigned int idx = (unsigned int)(sortbuf[r] & 0xFFFFULL);
            const float* bp = boxes_all + (size_t)idx * 4;
            b0 = bp[0]; b1 = bp[1]; b2 = bp[2]; b3 = bp[3];
        }
        sbox[r * 4 + 0] = b0; sbox[r * 4 + 1] = b1;
        sbox[r * 4 + 2] = b2; sbox[r * 4 + 3] = b3;
        areas[r] = (b2 - b0) * (b3 - b1);
        if (r < NPRE) {
            bool valid = ((b2 - b0) >= 16.0f) && ((b3 - b1) >= 16.0f);
            if (!valid) atomicOr(&suppr[r >> 6], 1ULL << (r & 63));
        }
    }
}

// ---------------------------------------------------------------------------
// K4: pairwise IoU bit mask, upper-triangle layout. Grid (188,4) x 256 thr.
// ---------------------------------------------------------------------------
__global__ __launch_bounds__(256, 1)
void k_mask(const float* __restrict__ sbox, const float* __restrict__ areas,
            unsigned long long* __restrict__ mask)
{
    const int cj = blockIdx.x, q = blockIdx.y;
    __shared__ float4 bx[64];
    __shared__ float aj[64];
    const int t = threadIdx.x;
    const int j0 = cj * 64;
    if (t < 64) { bx[t] = ((const float4*)sbox)[j0 + t]; aj[t] = areas[j0 + t]; }
    __syncthreads();
    const int c0 = ((cj + 1) * q) >> 2, c1 = ((cj + 1) * (q + 1)) >> 2;
    for (int i0 = c0 * 64; i0 < c1 * 64; i0 += 256) {
        int i = i0 + t;
        if (i < c1 * 64) {
            const float4 p = ((const float4*)sbox)[i];
            const float ai = areas[i];
            unsigned long long w = 0;
            for (int jj = 0; jj < 64; ++jj) {
                float4 qb = bx[jj];
                float yy1 = fmaxf(p.x, qb.x), xx1 = fmaxf(p.y, qb.y);
                float yy2 = fminf(p.z, qb.z), xx2 = fminf(p.w, qb.w);
                float inter = fmaxf(yy2 - yy1, 0.f) * fmaxf(xx2 - xx1, 0.f);
                float iou = inter / (ai + aj[jj] - inter + 1e-10f);
                w |= ((unsigned long long)((iou > 0.7f) && (j0 + jj > i))) << jj;
            }
            int ci = i >> 6;
            mask[(size_t)(tribase(ci) + (cj - ci)) * 64 + (i & 63)] = w;
        }
    }
}

// ---------------------------------------------------------------------------
// K5: sequential greedy scan. r13: speculative candidate prefetch.
// r12 post-mortem: the propagate phase's ~2 dependent memory rounds (after kw
// is known) dominate the 360us. Invariant: kw = ~curw <= ~rvs[c] = cand, and
// cand is known BEFORE the chain. Each propagate thread prefetches its rows
// for up to 48 candidate bits early (latency hides under chain+barrier);
// propagate is then pure VALU (conditional OR of prefetched rows). cand is
// thread-uniform -> identical ctz walk in prefetch and consume; all m[i]
// indices compile-time (no scratch). Overflow bits (>48 candidates, early
// chunks only) fall back to 8-wide on-demand loads.
// ---------------------------------------------------------------------------
__global__ __launch_bounds__(256, 1)
void k_scan(const unsigned long long* __restrict__ mask,
            const unsigned long long* __restrict__ suppr,
            const float* __restrict__ sbox, float* __restrict__ rois)
{
    constexpr int KPF = 48;
    __shared__ unsigned long long rvs[NW];
    __shared__ unsigned long long curw;
    __shared__ unsigned long long keptw[NW];
    __shared__ unsigned long long diagbuf[2][64];
    __shared__ int totkept, brk;
    __shared__ int pref[NW + 1];
    const int tid = threadIdx.x;
    if (tid < NW) { rvs[tid] = suppr[tid]; keptw[tid] = 0ULL; }
    if (tid == 0) { totkept = 0; brk = 0; }
    if (tid < 64) diagbuf[0][tid] = mask[tid];   // diag(0): tribase(0)=0
    __syncthreads();
    for (int c = 0; c < NW; ++c) {
        unsigned long long pf = 0;
        const bool isPf = (tid >= 64 && tid < 128 && c + 1 < NW);
        if (isPf) pf = mask[((size_t)tribase(c + 1)) * 64 + (tid - 64)];

        // ---- speculative candidate prefetch (before the chain) ----
        const bool isProp = (tid > c && tid < NW);
        const unsigned long long cand = isProp ? ~rvs[c] : 0ULL;
        const unsigned long long* mrow =
            mask + (size_t)(tribase(c) + (isProp ? (tid - c) : 1)) * 64;
        unsigned long long m[KPF];
        unsigned long long cl = cand;
#pragma unroll
        for (int i = 0; i < KPF; ++i) {
            if (cl) {
                int b = (int)__builtin_ctzll(cl); cl &= cl - 1;
                m[i] = mrow[b];
            } else m[i] = 0;
        }
        const unsigned long long crem = cl;    // candidates beyond the window

        if (tid < 64) {
            unsigned long long diag = diagbuf[c & 1][tid];
            unsigned long long w = rvs[c];
            unsigned long long un = ~w;          // unprocessed candidates
            while (un) {
                int b = (int)__builtin_ctzll(un);            // next kept bit
                unsigned long long db = __shfl(diag, b, 64); // its supp. row
                w |= db;
                un &= ~(db | (1ULL << b));
            }
            if (tid == 0) {
                curw = w;
                keptw[c] = ~w;
                totkept += __popcll(~w);
                if (totkept >= NPOST) brk = 1;
            }
        }
        __syncthreads();
        if (brk) break;
        unsigned long long kw = ~curw;           // kept bits; kw subset of cand
        if (isProp && kw) {
            unsigned long long acc = 0;
            unsigned long long cl2 = cand;
#pragma unroll
            for (int i = 0; i < KPF; ++i) {
                if (cl2) {
                    int b = (int)__builtin_ctzll(cl2); cl2 &= cl2 - 1;
                    if ((kw >> b) & 1ULL) acc |= m[i];
                }
            }
            unsigned long long rem = kw & crem;  // kept beyond window (rare)
            while (rem) {
                unsigned long long m0 = 0, m1 = 0, m2 = 0, m3 = 0,
                                   m4 = 0, m5 = 0, m6 = 0, m7 = 0;
                int b = (int)__builtin_ctzll(rem); m0 = mrow[b]; rem &= rem - 1;
                if (rem) { b = (int)__builtin_ctzll(rem); m1 = mrow[b]; rem &= rem - 1; }
                if (rem) { b = (int)__builtin_ctzll(rem); m2 = mrow[b]; rem &= rem - 1; }
                if (rem) { b = (int)__builtin_ctzll(rem); m3 = mrow[b]; rem &= rem - 1; }
                if (rem) { b = (int)__builtin_ctzll(rem); m4 = mrow[b]; rem &= rem - 1; }
                if (rem) { b = (int)__builtin_ctzll(rem); m5 = mrow[b]; rem &= rem - 1; }
                if (rem) { b = (int)__builtin_ctzll(rem); m6 = mrow[b]; rem &= rem - 1; }
                if (rem) { b = (int)__builtin_ctzll(rem); m7 = mrow[b]; rem &= rem - 1; }
                acc |= ((m0 | m1) | (m2 | m3)) | ((m4 | m5) | (m6 | m7));
            }
            rvs[tid] |= acc;
        }
        if (isPf) diagbuf[(c + 1) & 1][tid - 64] = pf;
        __syncthreads();
    }
    __syncthreads();
    if (tid == 0) {
        int s = 0;
        for (int c = 0; c < NW; ++c) { pref[c] = s; s += __popcll(keptw[c]); }
        pref[NW] = s;
    }
    __syncthreads();
    int total = pref[NW]; if (total > NPOST) total = NPOST;
    for (int r = total * 4 + tid; r < NPOST * 4; r += 256) rois[r] = 0.f;
    if (tid < NW) {
        unsigned long long kw = keptw[tid];
        int r = pref[tid];
        for (int b = 0; b < 64; ++b) {
            if ((kw >> b) & 1ULL) {
                if (r < NPOST) {
                    const float* bp = sbox + (size_t)(tid * 64 + b) * 4;
                    rois[r * 4 + 0] = bp[0]; rois[r * 4 + 1] = bp[1];
                    rois[r * 4 + 2] = bp[2]; rois[r * 4 + 3] = bp[3];
                }
                ++r;
            }
        }
    }
}

// ---------------------------------------------------------------------------
extern "C" void kernel_launch(void* const* d_in, const int* in_sizes, int n_in,
                              void* d_out, int out_size, void* d_ws, size_t ws_size,
                              hipStream_t stream)
{
    const float* x       = (const float*)d_in[0];
    const float* conv_w  = (const float*)d_in[1];
    const float* conv_b  = (const float*)d_in[2];
    const float* score_w = (const float*)d_in[3];
    const float* score_b = (const float*)d_in[4];
    const float* loc_w   = (const float*)d_in[5];
    const float* loc_b   = (const float*)d_in[6];
    const int*   imh     = (const int*)d_in[7];
    const int*   imw     = (const int*)d_in[8];
    float* out = (float*)d_out;
    char* ws = (char*)d_ws;
    float* h                    = (float*)(ws);                         // 8388608
    float* boxes_all            = (float*)(ws + 8388608);               // 589824
    unsigned long long* keys64  = (unsigned long long*)(ws + 8978432);  // 294912
    float* sbox                 = (float*)(ws + 9273344);               // 192512
    float* areas                = (float*)(ws + 9465856);               // 48128
    unsigned long long* suppr   = (unsigned long long*)(ws + 9513984);  // 1536
    unsigned long long* sortbuf = (unsigned long long*)(ws + 9515520);  // 131072
    unsigned long long* mask    = (unsigned long long*)(ws + 9646592);  // 9096192

    k_conv_mfma<<<512, 256, 0, stream>>>(x, conv_w, conv_b, h);
    k_heads <<<64, 256, 0, stream>>>(h, loc_w, loc_b, score_w, score_b, imh, imw,
                                     out, boxes_all, keys64);
    k_select<<<1, 1024, 0, stream>>>(keys64, boxes_all, sortbuf, sbox, areas, suppr);
    k_mask  <<<dim3(188, 4), 256, 0, stream>>>(sbox, areas, mask);
    k_scan  <<<1, 256, 0, stream>>>(mask, suppr, sbox, out + 221184);
}

// Round 14
// 1698.799 us; speedup vs baseline: 1.0686x; 1.0686x over previous
//
#include <hip/hip_runtime.h>
#include <cstdint>
#include <cstddef>
#include <math.h>

#define NANCH    36864
#define NPRE     12000
#define NPRE_PAD 12032
#define NW       188
#define SORT_N   16384
#define NPOST    2000

typedef double d4_t __attribute__((ext_vector_type(4)));

__device__ __forceinline__ int tribase(int ci) { return ci * NW - (ci * (ci - 1)) / 2; }

typedef __attribute__((address_space(1))) const void* as1cv_t;
typedef __attribute__((address_space(3))) void* as3v_t;
__device__ __forceinline__ void gload_lds16(const float* g, float* l)
{
    __builtin_amdgcn_global_load_lds((as1cv_t)g, (as3v_t)l, 16, 0, 0);
}

// ---------------------------------------------------------------------------
// K1: f64-MFMA implicit-GEMM 3x3 conv (1024ic -> 512oc, 64x64), bias+leaky
// fused, f32 h out. Grid 512 = 64 y x 8 oc-tiles (2 blk/CU). 4 waves (2x2),
// wave = 32x32 via 2x2 mfma_f64_16x16x4. Probe-calibrated lane maps (r4).
// r9 schedule (782us, MfmaUtil 68%): 2-ahead staging, counted vmcnt(12),
// step-0 reg preload. FROZEN — best measured configuration.
// ---------------------------------------------------------------------------
__global__ __launch_bounds__(256, 2)
void k_conv_mfma(const float* __restrict__ xg, const float* __restrict__ wg_,
                 const float* __restrict__ bg, float* __restrict__ hg)
{
    __shared__ __align__(16) float wlds[3][4608];   // 3 x 18 slots x (64oc x 4k)
    __shared__ __align__(16) float xlds[3][1632];   // 3 x 8ic x 3row x 68col
    const int tid = threadIdx.x;
    const int oct = blockIdx.x & 7;
    const int y   = blockIdx.x >> 3;
    const int oc0 = oct << 6;
    const int l   = tid & 63;       // lane
    const int wv  = tid >> 6;       // wave 0..3
    const int g   = l >> 4;         // k-group label
    const int li  = l & 15;
    const int wm  = wv >> 1;        // px-half
    const int wn  = wv & 1;         // oc-half
    const int slot5 = 16 + (wv & 1); // 5th gll slot (dup-identical for wv 2,3)

    // ---- layout probe (3 constant-input MFMAs) — proven in r4 ----
    int pr[4], qc[4];
    int aG = g;
    {
        d4_t Pz = {0., 0., 0., 0.}, Qz = {0., 0., 0., 0.}, Tz = {0., 0., 0., 0.};
        Pz = __builtin_amdgcn_mfma_f64_16x16x4f64((double)li, 1.0, Pz, 0, 0, 0);
        Qz = __builtin_amdgcn_mfma_f64_16x16x4f64(1.0, (double)li, Qz, 0, 0, 0);
        Tz = __builtin_amdgcn_mfma_f64_16x16x4f64((double)g, (double)(1 << (2 * g)),
                                                  Tz, 0, 0, 0);
        bool ok = true;
        const int tval = (int)Tz[0];
        if ((int)Tz[1] != tval || (int)Tz[2] != tval || (int)Tz[3] != tval) ok = false;
        int seen = 0;
#pragma unroll
        for (int j = 0; j < 4; ++j) {
            int d = (tval >> (2 * j)) & 3;
            seen |= 1 << d;
            if (d == g) aG = j;
        }
        if (seen != 15) ok = false;
#pragma unroll
        for (int r = 0; r < 4; ++r) {
            int pv = (int)Pz[r], qv = (int)Qz[r];
            if ((pv & 3) || (qv & 3)) ok = false;
            pr[r] = pv >> 2; qc[r] = qv >> 2;
            if (pr[r] > 15 || qc[r] > 15) ok = false;
        }
        if (!ok) {
#pragma unroll
            for (int r = 0; r < 4; ++r) { pr[r] = 4 * g + r; qc[r] = li; }
            aG = g;
        }
    }

    d4_t acc00 = {0., 0., 0., 0.}, acc01 = {0., 0., 0., 0.};
    d4_t acc10 = {0., 0., 0., 0.}, acc11 = {0., 0., 0., 0.};

    // x staging offsets: 8ic x 3row x 66col = 1584 floats / 256 thr -> 7 slots
    int xoff[7], loff[7];
#pragma unroll
    for (int t = 0; t < 7; ++t) {
        int f = tid + 256 * t;
        if (f < 1584) {
            int ic = f / 198; int r = f - ic * 198; int sr = r / 66; int gc = r - sr * 66;
            loff[t] = (ic * 3 + sr) * 68 + gc;
            int gy = y + sr - 1, gx = gc - 1;
            xoff[t] = (gy >= 0 && gy < 64 && gx >= 0 && gx < 64)
                      ? (ic * 4096 + gy * 64 + gx) : -1;
        } else { loff[t] = -1; xoff[t] = -1; }
    }
    int xoffL[7];                    // clamped: always-valid load address
#pragma unroll
    for (int t = 0; t < 7; ++t) xoffL[t] = (xoff[t] >= 0) ? xoff[t] : 0;

    const float* wsrc0 = wg_ + (size_t)(oc0 + l) * 9216;  // per-lane W row base
    const int abase = wm * 32 + li;
    const int bbase = (wn * 32 + li) * 4 + g;
    const int ax0   = (aG / 3) * 68 + (aG - 3 * (aG / 3)) + abase;  // step-0 A addr
    float xr[7];
    float fa0, fa1, fb0, fb1;
    double pa0, pa1, pb0, pb1;

    // ---- prologue: stage chunks 0,1; xr <- x(2); preload step0(0) ----
    {
#pragma unroll
        for (int i = 0; i < 4; ++i)
            gload_lds16(wsrc0 + 4 * (wv + 4 * i), &wlds[0][(wv + 4 * i) * 256]);
        gload_lds16(wsrc0 + 4 * slot5, &wlds[0][slot5 * 256]);
#pragma unroll
        for (int i = 0; i < 4; ++i)
            gload_lds16(wsrc0 + 72 + 4 * (wv + 4 * i), &wlds[1][(wv + 4 * i) * 256]);
        gload_lds16(wsrc0 + 72 + 4 * slot5, &wlds[1][slot5 * 256]);
#pragma unroll
        for (int t = 0; t < 7; ++t) xr[t] = xg[xoffL[t]];
#pragma unroll
        for (int t = 0; t < 7; ++t)
            if (loff[t] >= 0) xlds[0][loff[t]] = (xoff[t] >= 0) ? xr[t] : 0.f;
        {
            const float* xp = xg + 32768;
#pragma unroll
            for (int t = 0; t < 7; ++t) xr[t] = xp[xoffL[t]];
#pragma unroll
            for (int t = 0; t < 7; ++t)
                if (loff[t] >= 0) xlds[1][loff[t]] = (xoff[t] >= 0) ? xr[t] : 0.f;
        }
        {
            const float* xp = xg + 2 * 32768;
#pragma unroll
            for (int t = 0; t < 7; ++t) xr[t] = xp[xoffL[t]];
        }
        asm volatile("s_waitcnt lgkmcnt(0)" ::: "memory");
        asm volatile("s_waitcnt vmcnt(7)" ::: "memory");   // x(2) may still fly
        __builtin_amdgcn_s_barrier();
        fa0 = xlds[0][ax0]; fa1 = xlds[0][ax0 + 16];
        fb0 = wlds[0][bbase]; fb1 = wlds[0][bbase + 64];
        asm volatile("s_waitcnt lgkmcnt(0)" ::: "memory");
        pa0 = (double)fa0; pa1 = (double)fa1; pb0 = (double)fb0; pb1 = (double)fb1;
    }

#pragma unroll 1
    for (int cc = 0; cc < 128; ++cc) {
        int cb = cc % 3, nb = (cc + 1) % 3, sb = (cc + 2) % 3;
        if (cc + 2 < 128) {
            // stage chunk cc+2: exactly 5 gll + 7 x loads / thread
            const float* wsrc = wsrc0 + (cc + 2) * 72;
            float* wdst = &wlds[sb][0];
#pragma unroll
            for (int i = 0; i < 4; ++i)
                gload_lds16(wsrc + 4 * (wv + 4 * i), wdst + (wv + 4 * i) * 256);
            gload_lds16(wsrc + 4 * slot5, wdst + slot5 * 256);
            float* xdst = &xlds[sb][0];
#pragma unroll
            for (int t = 0; t < 7; ++t)
                if (loff[t] >= 0) xdst[loff[t]] = (xoff[t] >= 0) ? xr[t] : 0.f;
            {
                int nc = (cc + 3 < 128) ? (cc + 3) : 127;
                const float* xp = xg + (size_t)nc * 32768;
#pragma unroll
                for (int t = 0; t < 7; ++t) xr[t] = xp[xoffL[t]];
            }
            asm volatile("s_waitcnt vmcnt(12)" ::: "memory"); // staging(cc+1) landed
        } else {
            asm volatile("s_waitcnt vmcnt(0)" ::: "memory");
        }
        __builtin_amdgcn_s_barrier();                          // #1: publish buf[nb]
        __builtin_amdgcn_sched_barrier(0);

        // compute chunk cc: step0 from p-regs, steps 1..17 from LDS
        const float* wb = &wlds[cb][0];
        const float* xb = &xlds[cb][0];
        __builtin_amdgcn_s_setprio(1);
        acc00 = __builtin_amdgcn_mfma_f64_16x16x4f64(pa0, pb0, acc00, 0, 0, 0);
        acc01 = __builtin_amdgcn_mfma_f64_16x16x4f64(pa0, pb1, acc01, 0, 0, 0);
        acc10 = __builtin_amdgcn_mfma_f64_16x16x4f64(pa1, pb0, acc10, 0, 0, 0);
        acc11 = __builtin_amdgcn_mfma_f64_16x16x4f64(pa1, pb1, acc11, 0, 0, 0);
#pragma unroll
        for (int s = 1; s < 18; ++s) {
            int k   = 4 * s + aG;
            int icL = k / 9; int tap = k - 9 * icL;
            int ky  = tap / 3; int kx = tap - 3 * ky;
            int ax  = (icL * 3 + ky) * 68 + kx + abase;
            double a0 = (double)xb[ax];
            double a1 = (double)xb[ax + 16];
            double b0 = (double)wb[bbase + s * 256];
            double b1 = (double)wb[bbase + s * 256 + 64];
            acc00 = __builtin_amdgcn_mfma_f64_16x16x4f64(a0, b0, acc00, 0, 0, 0);
            acc01 = __builtin_amdgcn_mfma_f64_16x16x4f64(a0, b1, acc01, 0, 0, 0);
            acc10 = __builtin_amdgcn_mfma_f64_16x16x4f64(a1, b0, acc10, 0, 0, 0);
            acc11 = __builtin_amdgcn_mfma_f64_16x16x4f64(a1, b1, acc11, 0, 0, 0);
        }
        __builtin_amdgcn_s_setprio(0);
        __builtin_amdgcn_sched_barrier(0);   // pin compute reads before preload

        if (cc < 127) {
            // preload step0 of chunk cc+1 (buf[nb] published at bar#1 above)
            fa0 = xlds[nb][ax0]; fa1 = xlds[nb][ax0 + 16];
            fb0 = wlds[nb][bbase]; fb1 = wlds[nb][bbase + 64];
            asm volatile("s_waitcnt lgkmcnt(4)" ::: "memory"); // compute reads drained
            __builtin_amdgcn_s_barrier();                      // #2: reuse fence
            asm volatile("s_waitcnt lgkmcnt(0)" ::: "memory"); // preload landed
            pa0 = (double)fa0; pa1 = (double)fa1; pb0 = (double)fb0; pb1 = (double)fb1;
        } else {
            asm volatile("s_waitcnt lgkmcnt(0)" ::: "memory");
            __builtin_amdgcn_s_barrier();
        }
    }

    // epilogue: bias + leaky in f64, probe-derived labels, LDS transpose, f32 out
    __syncthreads();
    float* olds = &wlds[0][0];                    // 4352 floats needed <= 4608
    {
#pragma unroll
        for (int r = 0; r < 4; ++r) {
            const int oca = wn * 32 + qc[r];
            const int ocb = oca + 16;
            const double ba = (double)bg[oc0 + oca];
            const double bb = (double)bg[oc0 + ocb];
            const int pxa = wm * 32 + pr[r];
            const int pxb = pxa + 16;
            double t00 = acc00[r] + ba;
            double t01 = acc01[r] + bb;
            double t10 = acc10[r] + ba;
            double t11 = acc11[r] + bb;
            olds[oca * 68 + pxa] = (float)((t00 >= 0.0) ? t00 : 0.01 * t00);
            olds[ocb * 68 + pxa] = (float)((t01 >= 0.0) ? t01 : 0.01 * t01);
            olds[oca * 68 + pxb] = (float)((t10 >= 0.0) ? t10 : 0.01 * t10);
            olds[ocb * 68 + pxb] = (float)((t11 >= 0.0) ? t11 : 0.01 * t11);
        }
    }
    __syncthreads();
    {
        const int oc = tid >> 2, q = tid & 3;     // 4 threads per oc, 16 px each
        float* dst = hg + (size_t)(oc0 + oc) * 4096 + y * 64 + q * 16;
        const float* src = &olds[oc * 68 + q * 16];
#pragma unroll
        for (int j = 0; j < 4; ++j)
            *(float4*)(dst + 4 * j) = *(const float4*)(src + 4 * j);
    }
}

// ---------------------------------------------------------------------------
// K2: 1x1 convs (f64 accumulate) + f64 sort keys + anchors + f32 box deparam
// ---------------------------------------------------------------------------
__global__ __launch_bounds__(256, 1)
void k_heads(const float* __restrict__ hg, const float* __restrict__ loc_w,
             const float* __restrict__ loc_b, const float* __restrict__ score_w,
             const float* __restrict__ score_b, const int* __restrict__ imh,
             const int* __restrict__ imw, float* __restrict__ out,
             float* __restrict__ boxes_all, unsigned long long* __restrict__ keys64)
{
    __shared__ float  hch[64 * 64];
    __shared__ float  wch[54 * 64];
    __shared__ float  ol[54 * 64];
    __shared__ double sld[18 * 64];
    const int y = blockIdx.x, tid = threadIdx.x;
    const int px = tid & 63, cg = tid >> 6;
    double acc[14];
#pragma unroll
    for (int u = 0; u < 14; ++u) acc[u] = 0.0;
    for (int cc = 0; cc < 8; ++cc) {
        __syncthreads();
#pragma unroll
        for (int t = 0; t < 16; ++t) {
            int f = tid + 256 * t;
            hch[f] = hg[(size_t)(cc * 64 + (f >> 6)) * 4096 + y * 64 + (f & 63)];
        }
#pragma unroll
        for (int t = 0; t < 14; ++t) {
            int f = tid + 256 * t;
            if (f < 54 * 64) {
                int ch = f >> 6, c = f & 63;
                wch[f] = (ch < 36) ? loc_w[ch * 512 + cc * 64 + c]
                                   : score_w[(ch - 36) * 512 + cc * 64 + c];
            }
        }
        __syncthreads();
        for (int c = 0; c < 64; ++c) {
            double hvd = (double)hch[c * 64 + px];
#pragma unroll
            for (int u = 0; u < 14; ++u) {
                int ch = cg + 4 * u;
                if (ch < 54) acc[u] = fma((double)wch[ch * 64 + c], hvd, acc[u]);
            }
        }
    }
    __syncthreads();
#pragma unroll
    for (int u = 0; u < 14; ++u) {
        int ch = cg + 4 * u;
        if (ch < 54) {
            double s = acc[u] + (double)((ch < 36) ? loc_b[ch] : score_b[ch - 36]);
            ol[ch * 64 + px] = (float)s;
            if (ch >= 36) sld[(ch - 36) * 64 + px] = s;
        }
    }
    __syncthreads();
    for (int f = tid; f < 64 * 36; f += 256) {
        int p = f / 36, ch = f - 36 * p;
        out[(size_t)(y * 64 + p) * 36 + ch] = ol[ch * 64 + p];
    }
    for (int f = tid; f < 64 * 18; f += 256) {
        int p = f / 18, ch = f - 18 * p;
        out[147456 + (size_t)(y * 64 + p) * 18 + ch] = ol[(36 + ch) * 64 + p];
    }
    const float fy = (float)(*imh), fx = (float)(*imw);
    float* anch = out + 229184;
    for (int t2 = tid; t2 < 576; t2 += 256) {
        int p = t2 / 9, a = t2 - 9 * p;
        int pg = y * 64 + p;
        int ar = a / 3, as = a - 3 * ar;
        double rr = (ar == 0) ? 0.5 : ((ar == 1) ? 1.0 : 2.0);
        double ss = (as == 0) ? 8.0 : ((as == 1) ? 16.0 : 32.0);
        double hh = 16.0 * ss * sqrt(rr), wwd = 16.0 * ss * sqrt(1.0 / rr);
        float by1 = (float)(8.0 - hh * 0.5), bx1 = (float)(8.0 - wwd * 0.5);
        float by2 = (float)(8.0 + hh * 0.5), bx2 = (float)(8.0 + wwd * 0.5);
        float sy = (float)(y * 16), sx = (float)(p * 16);
        float a0 = sy + by1, a1 = sx + bx1, a2 = sy + by2, a3 = sx + bx2;
        int base = (pg * 9 + a) * 4;
        anch[base + 0] = a0; anch[base + 1] = a1; anch[base + 2] = a2; anch[base + 3] = a3;
        double d = sld[(a * 2 + 1) * 64 + p] - sld[(a * 2) * 64 + p];
        long long bits = __double_as_longlong(d);
        unsigned long long u64 =
            (unsigned long long)(bits ^ ((bits >> 63) | (long long)0x8000000000000000LL));
        unsigned long long v = ~u64;
        keys64[pg * 9 + a] = (v & 0xFFFFFFFFFFFF0000ULL) | (unsigned long long)(pg * 9 + a);
        float dy = ol[(a * 4 + 0) * 64 + p], dxv = ol[(a * 4 + 1) * 64 + p];
        float dh = ol[(a * 4 + 2) * 64 + p], dwv = ol[(a * 4 + 3) * 64 + p];
        float hA = a2 - a0, wA = a3 - a1;
        float cya = a0 + 0.5f * hA, cxa = a1 + 0.5f * wA;
        float cy = dy * hA + cya, cx = dxv * wA + cxa;
        float hb = hA * expf(dh), wb = wA * expf(dwv);
        float b0 = fminf(fmaxf(cy - 0.5f * hb, 0.f), fy);
        float b1 = fminf(fmaxf(cx - 0.5f * wb, 0.f), fx);
        float b2 = fminf(fmaxf(cy + 0.5f * hb, 0.f), fy);
        float b3 = fminf(fmaxf(cx + 0.5f * wb, 0.f), fx);
        boxes_all[base + 0] = b0; boxes_all[base + 1] = b1;
        boxes_all[base + 2] = b2; boxes_all[base + 3] = b3;
    }
}

// ---------------------------------------------------------------------------
// K3: radix-select 12000 smallest, compact, LDS-tiled bitonic sort.
// ---------------------------------------------------------------------------
__global__ __launch_bounds__(1024, 1)
void k_select(const unsigned long long* __restrict__ keys64,
              const float* __restrict__ boxes_all,
              unsigned long long* __restrict__ sortbuf, float* __restrict__ sbox,
              float* __restrict__ areas, unsigned long long* __restrict__ suppr)
{
    __shared__ unsigned int hist[256];
    __shared__ unsigned int sh_below, sh_prefix, sh_nsel;
    __shared__ unsigned long long tile[4096];
    const int tid = threadIdx.x;
    if (tid == 0) { sh_below = 0; sh_prefix = 0; sh_nsel = 0; }
    __syncthreads();
    for (int p = 3; p >= 0; --p) {
        if (tid < 256) hist[tid] = 0;
        __syncthreads();
        unsigned int pref = sh_prefix;
        int shift = p * 8;
        for (int i = tid; i < NANCH; i += 1024) {
            unsigned int k = (unsigned int)(keys64[i] >> 32);
            bool match = (p == 3) || ((k >> (shift + 8)) == pref);
            if (match) atomicAdd(&hist[(k >> shift) & 255u], 1u);
        }
        __syncthreads();
        if (tid == 0) {
            unsigned int below = sh_below, cacc = 0;
            int b = 0;
            for (; b < 256; ++b) {
                if (below + cacc + hist[b] >= NPRE) break;
                cacc += hist[b];
            }
            if (b > 255) b = 255;
            sh_below = below + cacc;
            sh_prefix = (pref << 8) | (unsigned int)b;
        }
        __syncthreads();
    }
    const unsigned int P = sh_prefix;
    for (int i = tid; i < NANCH; i += 1024) {
        unsigned long long k = keys64[i];
        if ((unsigned int)(k >> 32) <= P) {
            unsigned int pos = atomicAdd(&sh_nsel, 1u);
            if (pos < SORT_N) sortbuf[pos] = k;
        }
    }
    __syncthreads();
    unsigned int nsel = sh_nsel; if (nsel > SORT_N) nsel = SORT_N;
    for (unsigned int i = nsel + tid; i < SORT_N; i += 1024) sortbuf[i] = ~0ULL;
    __syncthreads();
    for (int T = 0; T < 4; ++T) {
        for (int t = tid; t < 4096; t += 1024) tile[t] = sortbuf[T * 4096 + t];
        __syncthreads();
        for (int k2 = 2; k2 <= 4096; k2 <<= 1) {
            for (int j = k2 >> 1; j > 0; j >>= 1) {
                for (int t = tid; t < 2048; t += 1024) {
                    int i = ((t & ~(j - 1)) << 1) | (t & (j - 1));
                    int ip = i | j;
                    bool up = (((T * 4096 + i) & k2) == 0);
                    unsigned long long A = tile[i], B = tile[ip];
                    if ((A > B) == up) { tile[i] = B; tile[ip] = A; }
                }
                __syncthreads();
            }
        }
        for (int t = tid; t < 4096; t += 1024) sortbuf[T * 4096 + t] = tile[t];
        __syncthreads();
    }
    auto gstage = [&](int k2, int j) {
        for (int t = tid; t < 8192; t += 1024) {
            int i = ((t & ~(j - 1)) << 1) | (t & (j - 1));
            int ip = i | j;
            bool up = ((i & k2) == 0);
            unsigned long long A = sortbuf[i], B = sortbuf[ip];
            if ((A > B) == up) { sortbuf[i] = B; sortbuf[ip] = A; }
        }
        __syncthreads();
    };
    auto ltail = [&](int k2) {
        for (int T = 0; T < 4; ++T) {
            for (int t = tid; t < 4096; t += 1024) tile[t] = sortbuf[T * 4096 + t];
            __syncthreads();
            for (int j = 2048; j > 0; j >>= 1) {
                for (int t = tid; t < 2048; t += 1024) {
                    int i = ((t & ~(j - 1)) << 1) | (t & (j - 1));
                    int ip = i | j;
                    bool up = (((T * 4096 + i) & k2) == 0);
                    unsigned long long A = tile[i], B = tile[ip];
                    if ((A > B) == up) { tile[i] = B; tile[ip] = A; }
                }
                __syncthreads();
            }
            for (int t = tid; t < 4096; t += 1024) sortbuf[T * 4096 + t] = tile[t];
            __syncthreads();
        }
    };
    gstage(8192, 4096);  ltail(8192);
    gstage(16384, 8192); gstage(16384, 4096); ltail(16384);

    if (tid < NW) suppr[tid] = (tid == NW - 1) ? 0xFFFFFFFF00000000ULL : 0ULL;
    __syncthreads();
    for (int r = tid; r < NPRE_PAD; r += 1024) {
        float b0 = 0, b1 = 0, b2 = 0, b3 = 0;
        if (r < NPRE) {
            unsigned int idx = (unsigned int)(sortbuf[r] & 0xFFFFULL);
            const float* bp = boxes_all + (size_t)idx * 4;
            b0 = bp[0]; b1 = bp[1]; b2 = bp[2]; b3 = bp[3];
        }
        sbox[r * 4 + 0] = b0; sbox[r * 4 + 1] = b1;
        sbox[r * 4 + 2] = b2; sbox[r * 4 + 3] = b3;
        areas[r] = (b2 - b0) * (b3 - b1);
        if (r < NPRE) {
            bool valid = ((b2 - b0) >= 16.0f) && ((b3 - b1) >= 16.0f);
            if (!valid) atomicOr(&suppr[r >> 6], 1ULL << (r & 63));
        }
    }
}

// ---------------------------------------------------------------------------
// K4: pairwise IoU bit mask, upper-triangle layout. Grid (188,4) x 256 thr.
// ---------------------------------------------------------------------------
__global__ __launch_bounds__(256, 1)
void k_mask(const float* __restrict__ sbox, const float* __restrict__ areas,
            unsigned long long* __restrict__ mask)
{
    const int cj = blockIdx.x, q = blockIdx.y;
    __shared__ float4 bx[64];
    __shared__ float aj[64];
    const int t = threadIdx.x;
    const int j0 = cj * 64;
    if (t < 64) { bx[t] = ((const float4*)sbox)[j0 + t]; aj[t] = areas[j0 + t]; }
    __syncthreads();
    const int c0 = ((cj + 1) * q) >> 2, c1 = ((cj + 1) * (q + 1)) >> 2;
    for (int i0 = c0 * 64; i0 < c1 * 64; i0 += 256) {
        int i = i0 + t;
        if (i < c1 * 64) {
            const float4 p = ((const float4*)sbox)[i];
            const float ai = areas[i];
            unsigned long long w = 0;
            for (int jj = 0; jj < 64; ++jj) {
                float4 qb = bx[jj];
                float yy1 = fmaxf(p.x, qb.x), xx1 = fmaxf(p.y, qb.y);
                float yy2 = fminf(p.z, qb.z), xx2 = fminf(p.w, qb.w);
                float inter = fmaxf(yy2 - yy1, 0.f) * fmaxf(xx2 - xx1, 0.f);
                float iou = inter / (ai + aj[jj] - inter + 1e-10f);
                w |= ((unsigned long long)((iou > 0.7f) && (j0 + jj > i))) << jj;
            }
            int ci = i >> 6;
            mask[(size_t)(tribase(ci) + (cj - ci)) * 64 + (i & 63)] = w;
        }
    }
}

// ---------------------------------------------------------------------------
// K5: sequential greedy scan (best-measured r8/r9 version: wave1 diag
// prefetch to LDS + 8-wide ctz propagate). r12's kept-bit chain was a null;
// r13's speculative prefetch regressed (flooded the memory pipe). Reverted.
// ---------------------------------------------------------------------------
__global__ __launch_bounds__(256, 1)
void k_scan(const unsigned long long* __restrict__ mask,
            const unsigned long long* __restrict__ suppr,
            const float* __restrict__ sbox, float* __restrict__ rois)
{
    __shared__ unsigned long long rvs[NW];
    __shared__ unsigned long long curw;
    __shared__ unsigned long long keptw[NW];
    __shared__ unsigned long long diagbuf[2][64];
    __shared__ int totkept, brk;
    __shared__ int pref[NW + 1];
    const int tid = threadIdx.x;
    if (tid < NW) { rvs[tid] = suppr[tid]; keptw[tid] = 0ULL; }
    if (tid == 0) { totkept = 0; brk = 0; }
    if (tid < 64) diagbuf[0][tid] = mask[tid];   // diag(0): tribase(0)=0
    __syncthreads();
    for (int c = 0; c < NW; ++c) {
        unsigned long long pf = 0;
        const bool isPf = (tid >= 64 && tid < 128 && c + 1 < NW);
        if (isPf) pf = mask[((size_t)tribase(c + 1)) * 64 + (tid - 64)];
        if (tid < 64) {
            unsigned long long diag = diagbuf[c & 1][tid];
            unsigned long long w = rvs[c];
            for (int b = 0; b < 64; ++b) {
                unsigned long long db = __shfl(diag, b, 64);
                if (!((w >> b) & 1ULL)) w |= db;
            }
            if (tid == 0) {
                curw = w;
                keptw[c] = ~w;
                totkept += __popcll(~w);
                if (totkept >= NPOST) brk = 1;
            }
        }
        __syncthreads();
        if (brk) break;
        unsigned long long kw = ~curw;
        if (kw && tid > c && tid < NW) {
            const unsigned long long* mrow = mask + (size_t)(tribase(c) + (tid - c)) * 64;
            unsigned long long acc = 0;
            while (kw) {
                unsigned long long m0 = 0, m1 = 0, m2 = 0, m3 = 0,
                                   m4 = 0, m5 = 0, m6 = 0, m7 = 0;
                int b = (int)__builtin_ctzll(kw); m0 = mrow[b]; kw &= kw - 1;
                if (kw) { b = (int)__builtin_ctzll(kw); m1 = mrow[b]; kw &= kw - 1; }
                if (kw) { b = (int)__builtin_ctzll(kw); m2 = mrow[b]; kw &= kw - 1; }
                if (kw) { b = (int)__builtin_ctzll(kw); m3 = mrow[b]; kw &= kw - 1; }
                if (kw) { b = (int)__builtin_ctzll(kw); m4 = mrow[b]; kw &= kw - 1; }
                if (kw) { b = (int)__builtin_ctzll(kw); m5 = mrow[b]; kw &= kw - 1; }
                if (kw) { b = (int)__builtin_ctzll(kw); m6 = mrow[b]; kw &= kw - 1; }
                if (kw) { b = (int)__builtin_ctzll(kw); m7 = mrow[b]; kw &= kw - 1; }
                acc |= ((m0 | m1) | (m2 | m3)) | ((m4 | m5) | (m6 | m7));
            }
            rvs[tid] |= acc;
        }
        if (isPf) diagbuf[(c + 1) & 1][tid - 64] = pf;
        __syncthreads();
    }
    __syncthreads();
    if (tid == 0) {
        int s = 0;
        for (int c = 0; c < NW; ++c) { pref[c] = s; s += __popcll(keptw[c]); }
        pref[NW] = s;
    }
    __syncthreads();
    int total = pref[NW]; if (total > NPOST) total = NPOST;
    for (int r = total * 4 + tid; r < NPOST * 4; r += 256) rois[r] = 0.f;
    if (tid < NW) {
        unsigned long long kw = keptw[tid];
        int r = pref[tid];
        for (int b = 0; b < 64; ++b) {
            if ((kw >> b) & 1ULL) {
                if (r < NPOST) {
                    const float* bp = sbox + (size_t)(tid * 64 + b) * 4;
                    rois[r * 4 + 0] = bp[0]; rois[r * 4 + 1] = bp[1];
                    rois[r * 4 + 2] = bp[2]; rois[r * 4 + 3] = bp[3];
                }
                ++r;
            }
        }
    }
}

// ---------------------------------------------------------------------------
extern "C" void kernel_launch(void* const* d_in, const int* in_sizes, int n_in,
                              void* d_out, int out_size, void* d_ws, size_t ws_size,
                              hipStream_t stream)
{
    const float* x       = (const float*)d_in[0];
    const float* conv_w  = (const float*)d_in[1];
    const float* conv_b  = (const float*)d_in[2];
    const float* score_w = (const float*)d_in[3];
    const float* score_b = (const float*)d_in[4];
    const float* loc_w   = (const float*)d_in[5];
    const float* loc_b   = (const float*)d_in[6];
    const int*   imh     = (const int*)d_in[7];
    const int*   imw     = (const int*)d_in[8];
    float* out = (float*)d_out;
    char* ws = (char*)d_ws;
    float* h                    = (float*)(ws);                         // 8388608
    float* boxes_all            = (float*)(ws + 8388608);               // 589824
    unsigned long long* keys64  = (unsigned long long*)(ws + 8978432);  // 294912
    float* sbox                 = (float*)(ws + 9273344);               // 192512
    float* areas                = (float*)(ws + 9465856);               // 48128
    unsigned long long* suppr   = (unsigned long long*)(ws + 9513984);  // 1536
    unsigned long long* sortbuf = (unsigned long long*)(ws + 9515520);  // 131072
    unsigned long long* mask    = (unsigned long long*)(ws + 9646592);  // 9096192

    k_conv_mfma<<<512, 256, 0, stream>>>(x, conv_w, conv_b, h);
    k_heads <<<64, 256, 0, stream>>>(h, loc_w, loc_b, score_w, score_b, imh, imw,
                                     out, boxes_all, keys64);
    k_select<<<1, 1024, 0, stream>>>(keys64, boxes_all, sortbuf, sbox, areas, suppr);
    k_mask  <<<dim3(188, 4), 256, 0, stream>>>(sbox, areas, mask);
    k_scan  <<<1, 256, 0, stream>>>(mask, suppr, sbox, out + 221184);
}